// Round 1
// 560.456 us; speedup vs baseline: 1.2036x; 1.2036x over previous
//
#include <hip/hip_runtime.h>
#include <cstdint>
#include <cstddef>

typedef unsigned int u32;
typedef unsigned short u16;
typedef __bf16 bf16x8 __attribute__((ext_vector_type(8)));
typedef float f32x16 __attribute__((ext_vector_type(16)));
typedef float f32x4v __attribute__((ext_vector_type(4)));

#define DEV static __device__ __forceinline__

DEV u16 f2bf(float f){ u32 u=__float_as_uint(f); return (u16)((u + 0x7FFFu + ((u>>16)&1u))>>16); }
DEV uint2 cvt4(float4 v){
  uint2 r;
  r.x = (u32)f2bf(v.x) | ((u32)f2bf(v.y)<<16);
  r.y = (u32)f2bf(v.z) | ((u32)f2bf(v.w)<<16);
  return r;
}
DEV uint2 cvt4(f32x4v v){
  uint2 r;
  r.x = (u32)f2bf(v.x) | ((u32)f2bf(v.y)<<16);
  r.y = (u32)f2bf(v.z) | ((u32)f2bf(v.w)<<16);
  return r;
}
DEV u32 lrelu_pk(u32 u){
  float lo=__uint_as_float(u<<16);
  float hi=__uint_as_float(u&0xFFFF0000u);
  lo=fmaxf(lo,0.01f*lo); hi=fmaxf(hi,0.01f*hi);
  return (u32)f2bf(lo) | (((u32)f2bf(hi))<<16);
}

// ---------------------------------------------------------------------------
// Pre-pack f32 weights into bf16 MFMA B-fragment order + detect mask dtype.
// B-frag (32x32x16): n = lane&31, k = kk*16 + (lane>>5)*8 + j
// ---------------------------------------------------------------------------
__global__ void k_prepack(const float* __restrict__ Wc, const float* __restrict__ Wca,
    const float* __restrict__ Wex, const float* __restrict__ Wey, const float* __restrict__ We,
    const unsigned char* __restrict__ maskb,
    u16* __restrict__ wpc, u16* __restrict__ wpx, u16* __restrict__ wpy,
    u16* __restrict__ wpe, int* __restrict__ flags)
{
  int idx = blockIdx.x*256 + threadIdx.x;
  {
    int t=idx>>13, kk=(idx>>9)&15, ln=(idx>>3)&63, j=idx&7;
    int n=t*32+(ln&31), k=kk*16+(ln>>5)*8+j;
    if (idx < 73728){           // Wc (256 out) + Wca (8 out) + zero-pad -> 9 tiles
      float v;
      if (t<8) v = Wc[n*256+k];
      else { int n2=n-256; v = (n2<8) ? Wca[n2*256+k] : 0.f; }
      wpc[idx]=f2bf(v);
    }
    if (idx < 65536){ wpx[idx]=f2bf(Wex[n*256+k]); wpy[idx]=f2bf(Wey[n*256+k]); }
  }
  if (idx < 32768){             // We: K=512 -> 32 kk, 2 tiles
    int t=idx>>14, kk=(idx>>9)&31, ln=(idx>>3)&63, j=idx&7;
    int n=t*32+(ln&31), k=kk*16+(ln>>5)*8+j;
    wpe[idx]=f2bf(We[n*512+k]);
  }
  if (idx==0){                  // mask dtype sniffer (~90% ones)
    int c3f1=0,c3f3=0,nzoff=0,nz4m8=0,nz0=0;
    for (int i=0;i<256;i++){
      unsigned char b=maskb[i];
      if ((i&3)==1 && b==0x3F) c3f1++;
      if ((i&3)==3 && b==0x3F) c3f3++;
      if ((i&3)!=0 && b) nzoff++;
      if ((i&7)>=4 && b) nz4m8++;
      if ((i&7)==0 && b) nz0++;
    }
    int mode;
    if (c3f1>8) mode=2;                    // bf16
    else if (c3f3>8) mode=3;               // f32
    else if (nzoff>8) mode=0;              // bool / uint8
    else if (nz4m8==0 && nz0>4) mode=4;    // int64
    else mode=1;                           // int32
    flags[0]=mode;
  }
}

// ---------------------------------------------------------------------------
// AttentionContract: one workgroup per (b,l). f32 slab -> bf16 LDS (XOR
// swizzle on 16B granules), 9-tile 32x32x16 MFMA (tile 8 = Wca logits),
// LN in-register, masked softmax over y, weighted contraction.
// Round-1 change: weight-fragment loads batched 5+4 per kk with
// sched_barrier pinning (kills the serial L2-miss chain); ll staging uses
// non-temporal loads so the 268MB stream stops evicting the 147KB weights.
// ---------------------------------------------------------------------------
__global__ __launch_bounds__(256,2) void k_contract(
    const float* __restrict__ ll, const void* __restrict__ maskp,
    const u16* __restrict__ Wp, const float* __restrict__ bc, const float* __restrict__ bca,
    const float* __restrict__ gc, const float* __restrict__ bec,
    const int* __restrict__ flags, float* __restrict__ outc)
{
  __shared__ __attribute__((aligned(16))) union SMem {
    char slab[65536];                       // 128 rows * 512B bf16
    struct { float logit[1536]; float partial[1024]; } post;
  } sm;
  __shared__ float maskv[128];

  int tid=threadIdx.x, lane=tid&63, wave=tid>>6;
  int bl = blockIdx.x;
  const float* src = ll + (size_t)bl*(128*256);

  // stage: wave w rows [w*32, w*32+32); lane covers f32 cols [lane*4, +4)
  // nt loads: streaming data, keep L1/L2 for the weight working set.
  #pragma unroll 8
  for (int it=0;it<32;it++){
    int row = wave*32 + it;
    f32x4v v = __builtin_nontemporal_load((const f32x4v*)(src + row*256 + lane*4));
    uint2 pk = cvt4(v);
    *(uint2*)(sm.slab + row*512 + ((((lane>>1) ^ (row&31)))<<4) + (lane&1)*8) = pk;
  }
  if (tid < 128){
    int mode = flags[0];
    size_t mi = (size_t)bl*128 + tid;
    bool on;
    if (mode==0)      on = ((const unsigned char*)maskp)[mi] != 0;
    else if (mode==1) on = ((const int*)maskp)[mi] != 0;
    else if (mode==2) on = ((const u16*)maskp)[mi] != 0;
    else if (mode==4) on = ((const unsigned long long*)maskp)[mi] != 0ull;
    else              on = (((const u32*)maskp)[mi]<<1) != 0;
    maskv[tid] = on ? 1.f : 0.f;
  }
  __syncthreads();

  f32x16 acc[9];
  #pragma unroll
  for (int t=0;t<9;t++)
    #pragma unroll
    for (int i=0;i<16;i++) acc[t][i]=0.f;
  int y0 = wave*32;
  int arow = y0 + (lane&31);
  int axor = arow & 31;
  int half = lane>>5;
  const char* sb = sm.slab;
  const u16* wl = Wp + lane*8;
  for (int kk=0;kk<16;kk++){
    uint4 raw = *(const uint4*)(sb + arow*512 + (((kk*2+half) ^ axor)<<4));
    const u16* wk = wl + (size_t)kk*512;
    // batch-issue 5 weight fragments (independent 16B loads), pin the group
    bf16x8 b0 = *(const bf16x8*)(wk);
    bf16x8 b1 = *(const bf16x8*)(wk + 8192);
    bf16x8 b2 = *(const bf16x8*)(wk + 16384);
    bf16x8 b3 = *(const bf16x8*)(wk + 24576);
    bf16x8 b4 = *(const bf16x8*)(wk + 32768);
    __builtin_amdgcn_sched_barrier(0);
    uint4 t4; t4.x=lrelu_pk(raw.x); t4.y=lrelu_pk(raw.y); t4.z=lrelu_pk(raw.z); t4.w=lrelu_pk(raw.w);
    bf16x8 a = __builtin_bit_cast(bf16x8, t4);
    acc[0] = __builtin_amdgcn_mfma_f32_32x32x16_bf16(a, b0, acc[0], 0,0,0);
    acc[1] = __builtin_amdgcn_mfma_f32_32x32x16_bf16(a, b1, acc[1], 0,0,0);
    acc[2] = __builtin_amdgcn_mfma_f32_32x32x16_bf16(a, b2, acc[2], 0,0,0);
    acc[3] = __builtin_amdgcn_mfma_f32_32x32x16_bf16(a, b3, acc[3], 0,0,0);
    acc[4] = __builtin_amdgcn_mfma_f32_32x32x16_bf16(a, b4, acc[4], 0,0,0);
    // second batch of 4
    bf16x8 b5 = *(const bf16x8*)(wk + 40960);
    bf16x8 b6 = *(const bf16x8*)(wk + 49152);
    bf16x8 b7 = *(const bf16x8*)(wk + 57344);
    bf16x8 b8 = *(const bf16x8*)(wk + 65536);
    __builtin_amdgcn_sched_barrier(0);
    acc[5] = __builtin_amdgcn_mfma_f32_32x32x16_bf16(a, b5, acc[5], 0,0,0);
    acc[6] = __builtin_amdgcn_mfma_f32_32x32x16_bf16(a, b6, acc[6], 0,0,0);
    acc[7] = __builtin_amdgcn_mfma_f32_32x32x16_bf16(a, b7, acc[7], 0,0,0);
    acc[8] = __builtin_amdgcn_mfma_f32_32x32x16_bf16(a, b8, acc[8], 0,0,0);
  }
  __syncthreads();   // slab reads done; logit/partial overlay becomes live

  int col = lane & 31;
  float bv[8], gv[8], bev[8];
  #pragma unroll
  for (int t=0;t<8;t++){
    int n=t*32+col; bv[t]=bc[n]; gv[t]=gc[n]; bev[t]=bec[n];
  }
  float bcav = (col<8) ? bca[col] : 0.f;

  #pragma unroll
  for (int r=0;r<16;r++){
    int row=(r&3)+8*(r>>2)+4*half;
    float s=0.f, sq=0.f;
    #pragma unroll
    for (int t=0;t<8;t++){
      float v = acc[t][r] + bv[t]; acc[t][r]=v; s += v; sq = fmaf(v,v,sq);
    }
    #pragma unroll
    for (int m=1;m<=16;m<<=1){ s += __shfl_xor(s,m,64); sq += __shfl_xor(sq,m,64); }
    float mu = s*(1.f/256.f);
    float var = fmaf(sq,1.f/256.f, -mu*mu);
    float rin = rsqrtf(var+1e-5f);
    #pragma unroll
    for (int t=0;t<8;t++) acc[t][r] = fmaf((acc[t][r]-mu)*rin, gv[t], bev[t]);
    if (col<8) sm.post.logit[(y0+row)*12+col] = acc[8][r] + bcav;
  }
  __syncthreads();

  // masked softmax over y (len 128): 32 threads per head
  {
    int h = tid>>5, sub = tid&31;
    float lv[4], ev[4];
    #pragma unroll
    for (int j=0;j<4;j++) lv[j] = sm.post.logit[(sub+32*j)*12 + h];
    float mx = fmaxf(fmaxf(lv[0],lv[1]), fmaxf(lv[2],lv[3]));
    #pragma unroll
    for (int m=1;m<=16;m<<=1) mx = fmaxf(mx, __shfl_xor(mx,m,64));
    float ssum=0.f;
    #pragma unroll
    for (int j=0;j<4;j++){ ev[j] = __expf(lv[j]-mx)*maskv[sub+32*j]; ssum += ev[j]; }
    #pragma unroll
    for (int m=1;m<=16;m<<=1) ssum += __shfl_xor(ssum,m,64);
    float inv = 1.f/(ssum+1e-10f);
    #pragma unroll
    for (int j=0;j<4;j++) sm.post.logit[(sub+32*j)*12+h] = ev[j]*inv;
  }
  __syncthreads();

  // contraction: sum_y w[y,h] * of[y,n]
  float ctr[8];
  #pragma unroll
  for (int t=0;t<8;t++) ctr[t]=0.f;
  #pragma unroll
  for (int r=0;r<16;r++){
    int row=(r&3)+8*(r>>2)+4*half;
    const float* wr = &sm.post.logit[(y0+row)*12];
    float4 w0 = *(const float4*)wr;
    float4 w1 = *(const float4*)(wr+4);
    ctr[0]=fmaf(w0.x,acc[0][r],ctr[0]); ctr[1]=fmaf(w0.y,acc[1][r],ctr[1]);
    ctr[2]=fmaf(w0.z,acc[2][r],ctr[2]); ctr[3]=fmaf(w0.w,acc[3][r],ctr[3]);
    ctr[4]=fmaf(w1.x,acc[4][r],ctr[4]); ctr[5]=fmaf(w1.y,acc[5][r],ctr[5]);
    ctr[6]=fmaf(w1.z,acc[6][r],ctr[6]); ctr[7]=fmaf(w1.w,acc[7][r],ctr[7]);
  }
  #pragma unroll
  for (int t=0;t<8;t++) ctr[t] += __shfl_xor(ctr[t],32,64);
  if (lane<32){
    #pragma unroll
    for (int t=0;t<8;t++) sm.post.partial[wave*256 + t*32 + col] = ctr[t];
  }
  __syncthreads();
  float v = sm.post.partial[tid]+sm.post.partial[256+tid]
          + sm.post.partial[512+tid]+sm.post.partial[768+tid];
  outc[(size_t)bl*256 + tid] = v;
}

// ---------------------------------------------------------------------------
// NormAndLinear (lig_feat / rec_feat), f32 in -> bf16 ws out
// Same 4+4 batched weight loads as k_contract.
// ---------------------------------------------------------------------------
__global__ __launch_bounds__(256,2) void k_nl(
    const float* __restrict__ src, const u16* __restrict__ Wp,
    const float* __restrict__ bias, const float* __restrict__ g,
    const float* __restrict__ beta, u16* __restrict__ dst)
{
  __shared__ __attribute__((aligned(16))) char slab[65536];
  int tid=threadIdx.x, lane=tid&63, wave=tid>>6;
  const float* s0 = src + (size_t)blockIdx.x*(128*256);
  #pragma unroll 8
  for (int it=0;it<32;it++){
    int row = wave*32 + it;
    float4 v = *(const float4*)(s0 + row*256 + lane*4);
    uint2 pk = cvt4(v);
    *(uint2*)(slab + row*512 + ((((lane>>1) ^ (row&31)))<<4) + (lane&1)*8) = pk;
  }
  __syncthreads();

  f32x16 acc[8];
  #pragma unroll
  for (int t=0;t<8;t++)
    #pragma unroll
    for (int i=0;i<16;i++) acc[t][i]=0.f;
  int y0 = wave*32;
  int arow = y0 + (lane&31);
  int axor = arow & 31;
  int half = lane>>5;
  const u16* wl = Wp + lane*8;
  for (int kk=0;kk<16;kk++){
    uint4 raw = *(const uint4*)(slab + arow*512 + (((kk*2+half) ^ axor)<<4));
    const u16* wk = wl + (size_t)kk*512;
    bf16x8 b0 = *(const bf16x8*)(wk);
    bf16x8 b1 = *(const bf16x8*)(wk + 8192);
    bf16x8 b2 = *(const bf16x8*)(wk + 16384);
    bf16x8 b3 = *(const bf16x8*)(wk + 24576);
    __builtin_amdgcn_sched_barrier(0);
    uint4 t4; t4.x=lrelu_pk(raw.x); t4.y=lrelu_pk(raw.y); t4.z=lrelu_pk(raw.z); t4.w=lrelu_pk(raw.w);
    bf16x8 a = __builtin_bit_cast(bf16x8, t4);
    acc[0] = __builtin_amdgcn_mfma_f32_32x32x16_bf16(a, b0, acc[0], 0,0,0);
    acc[1] = __builtin_amdgcn_mfma_f32_32x32x16_bf16(a, b1, acc[1], 0,0,0);
    acc[2] = __builtin_amdgcn_mfma_f32_32x32x16_bf16(a, b2, acc[2], 0,0,0);
    acc[3] = __builtin_amdgcn_mfma_f32_32x32x16_bf16(a, b3, acc[3], 0,0,0);
    bf16x8 b4 = *(const bf16x8*)(wk + 32768);
    bf16x8 b5 = *(const bf16x8*)(wk + 40960);
    bf16x8 b6 = *(const bf16x8*)(wk + 49152);
    bf16x8 b7 = *(const bf16x8*)(wk + 57344);
    __builtin_amdgcn_sched_barrier(0);
    acc[4] = __builtin_amdgcn_mfma_f32_32x32x16_bf16(a, b4, acc[4], 0,0,0);
    acc[5] = __builtin_amdgcn_mfma_f32_32x32x16_bf16(a, b5, acc[5], 0,0,0);
    acc[6] = __builtin_amdgcn_mfma_f32_32x32x16_bf16(a, b6, acc[6], 0,0,0);
    acc[7] = __builtin_amdgcn_mfma_f32_32x32x16_bf16(a, b7, acc[7], 0,0,0);
  }
  int col = lane & 31;
  float bv[8], gv[8], bev[8];
  #pragma unroll
  for (int t=0;t<8;t++){
    int n=t*32+col; bv[t]=bias[n]; gv[t]=g[n]; bev[t]=beta[n];
  }
  #pragma unroll
  for (int r=0;r<16;r++){
    int row=(r&3)+8*(r>>2)+4*half;
    float s=0.f, sq=0.f;
    #pragma unroll
    for (int t=0;t<8;t++){
      float v = acc[t][r] + bv[t]; acc[t][r]=v; s += v; sq = fmaf(v,v,sq);
    }
    #pragma unroll
    for (int m=1;m<=16;m<<=1){ s += __shfl_xor(s,m,64); sq += __shfl_xor(sq,m,64); }
    float mu = s*(1.f/256.f);
    float var = fmaf(sq,1.f/256.f, -mu*mu);
    float rin = rsqrtf(var+1e-5f);
    size_t rowg = (size_t)blockIdx.x*128 + y0 + row;
    #pragma unroll
    for (int t=0;t<8;t++){
      float v = fmaf((acc[t][r]-mu)*rin, gv[t], bev[t]);
      dst[rowg*256 + t*32 + col] = f2bf(v);
    }
  }
}

// ---------------------------------------------------------------------------
// AttentionExpand: per (b, 32-y tile): C[x,y,h] = sum_f xf[x,h,f]*yf[y,h,f]
// 16x16x32 MFMA, LDS transpose, f32 output.
// ---------------------------------------------------------------------------
__global__ __launch_bounds__(256,2) void k_expand(
    const u16* __restrict__ xf, const u16* __restrict__ yf, float* __restrict__ oute)
{
  __shared__ __attribute__((aligned(16))) u16 ytile[32*264];
  __shared__ __attribute__((aligned(16))) float stage[4][2048];
  int tid=threadIdx.x, lane=tid&63, wave=tid>>6;
  int bi = blockIdx.x>>4, yt = blockIdx.x&15;

  #pragma unroll
  for (int i=0;i<4;i++){
    int idx=i*256+tid; int row=idx>>5, c=idx&31;
    uint4 v = *(const uint4*)(yf + ((size_t)(bi*512 + yt*32 + row))*256 + c*8);
    *(uint4*)((char*)ytile + row*528 + c*16) = v;
  }
  __syncthreads();

  bf16x8 af[2][8];
  #pragma unroll
  for (int xi=0;xi<2;xi++){
    int x = (wave*2+xi)*16 + (lane&15);
    #pragma unroll
    for (int h=0;h<8;h++)
      af[xi][h] = *(const bf16x8*)(xf + ((size_t)(bi*128+x))*256 + h*32 + (lane>>4)*8);
  }
  float* stw = stage[wave];
  #pragma unroll
  for (int xi=0;xi<2;xi++){
    #pragma unroll
    for (int nt=0;nt<2;nt++){
      #pragma unroll
      for (int h=0;h<8;h++){
        bf16x8 bv = *(const bf16x8*)((const char*)ytile + (nt*16+(lane&15))*528 + (h*32+(lane>>4)*8)*2);
        f32x4v c = {0.f,0.f,0.f,0.f};
        c = __builtin_amdgcn_mfma_f32_16x16x32_bf16(af[xi][h], bv, c, 0,0,0);
        #pragma unroll
        for (int q=0;q<4;q++){
          int xp=(lane>>4)*4+q, yp=lane&15;
          stw[(xp*16+yp)*8 + h] = c[q];
        }
      }
      __syncthreads();
      #pragma unroll
      for (int j=0;j<4;j++){
        int pi=j*64+lane, xp=pi>>4, yp=pi&15;
        const float* sp = &stw[(xp*16+yp)*8];
        float4 a = *(const float4*)sp;
        float4 b2 = *(const float4*)(sp+4);
        size_t x=(size_t)(wave*2+xi)*16+xp, y=(size_t)yt*32+nt*16+yp;
        float* po = oute + (((size_t)bi*128+x)*512 + y)*8;
        *(float4*)po = a;
        *(float4*)(po+4) = b2;
      }
      __syncthreads();
    }
  }
}

// ---------------------------------------------------------------------------
// Edges: gather 64 edges' concat rows -> bf16 LDS (XOR swizzle, 64 granules),
// 32x32x16 MFMA K=512 (2 waves), bias+lrelu, f32 atomicAdd scatter.
// Round-1: gather loop unrolled x4 for MLP; kk loop unrolled x2 with batched
// (4-wide) weight loads.
// ---------------------------------------------------------------------------
__global__ __launch_bounds__(128,1) void k_edges(
    const float* __restrict__ lig, const int* __restrict__ eb, const int* __restrict__ es,
    const int* __restrict__ ed, const u16* __restrict__ Wp, const float* __restrict__ bias,
    float* __restrict__ outl)
{
  __shared__ __attribute__((aligned(16))) char slab[65536];  // 64 edges * 1024B
  int tid=threadIdx.x, lane=tid&63, wave=tid>>6;  // 2 waves
  int e0 = blockIdx.x*64;
  int ge = e0 + wave*32 + (lane&31);
  int b0=eb[ge], s0=es[ge], d0=ed[ge];
  long long ps = (long long)(uintptr_t)(lig + ((size_t)(b0*128+s0))*256);
  long long pd = (long long)(uintptr_t)(lig + ((size_t)(b0*128+d0))*256);
  #pragma unroll 4
  for (int i=0;i<32;i++){
    int ri = wave*32 + i;
    const float* sp = (const float*)(uintptr_t)__shfl(ps, i, 32);
    const float* dp = (const float*)(uintptr_t)__shfl(pd, i, 32);
    #pragma unroll
    for (int j=0;j<2;j++){
      const float* base = j ? dp : sp;
      float4 v = *(const float4*)(base + lane*4);
      uint2 pk = cvt4(v);
      int g = j*32 + (lane>>1);
      *(uint2*)(slab + (size_t)ri*1024 + ((g ^ (ri&63))<<4) + (lane&1)*8) = pk;
    }
  }
  __syncthreads();

  f32x16 acc[2];
  #pragma unroll
  for (int t=0;t<2;t++)
    #pragma unroll
    for (int i=0;i<16;i++) acc[t][i]=0.f;
  int arow = wave*32 + (lane&31);
  int axor = arow & 63;
  int half = lane>>5;
  const u16* wl = Wp + lane*8;
  for (int kk=0;kk<32;kk+=2){
    uint4 raw0 = *(const uint4*)(slab + (size_t)arow*1024 + (((kk*2+half) ^ axor)<<4));
    uint4 raw1 = *(const uint4*)(slab + (size_t)arow*1024 + ((((kk+1)*2+half) ^ axor)<<4));
    const u16* wk = wl + (size_t)kk*512;
    bf16x8 b00 = *(const bf16x8*)(wk);
    bf16x8 b01 = *(const bf16x8*)(wk + 16384);
    bf16x8 b10 = *(const bf16x8*)(wk + 512);
    bf16x8 b11 = *(const bf16x8*)(wk + 16384 + 512);
    __builtin_amdgcn_sched_barrier(0);
    bf16x8 a0 = __builtin_bit_cast(bf16x8, raw0);   // lrelu is AFTER linear here
    bf16x8 a1 = __builtin_bit_cast(bf16x8, raw1);
    acc[0] = __builtin_amdgcn_mfma_f32_32x32x16_bf16(a0, b00, acc[0], 0,0,0);
    acc[1] = __builtin_amdgcn_mfma_f32_32x32x16_bf16(a0, b01, acc[1], 0,0,0);
    acc[0] = __builtin_amdgcn_mfma_f32_32x32x16_bf16(a1, b10, acc[0], 0,0,0);
    acc[1] = __builtin_amdgcn_mfma_f32_32x32x16_bf16(a1, b11, acc[1], 0,0,0);
  }
  int col = lane&31;
  float bv0=bias[col], bv1=bias[32+col];
  #pragma unroll
  for (int r=0;r<16;r++){
    int row=(r&3)+8*(r>>2)+4*half;
    int ee = e0 + wave*32 + row;
    int bb=eb[ee], ss=es[ee], dd=ed[ee];
    float* cell = outl + (((size_t)(bb*128+ss))*128 + (size_t)dd)*64;
    #pragma unroll
    for (int t=0;t<2;t++){
      float v = acc[t][r] + (t ? bv1 : bv0);
      v = fmaxf(v, 0.01f*v);
      atomicAdd(cell + t*32 + col, v);
    }
  }
}

// ---------------------------------------------------------------------------
extern "C" void kernel_launch(void* const* d_in, const int* in_sizes, int n_in,
                              void* d_out, int out_size, void* d_ws, size_t ws_size,
                              hipStream_t stream)
{
  (void)in_sizes; (void)n_in; (void)out_size; (void)ws_size;
  const float* ll  = (const float*)d_in[0];
  const float* lig = (const float*)d_in[1];
  const float* rec = (const float*)d_in[2];
  const void* mask = d_in[3];
  const int* eb = (const int*)d_in[4];
  const int* es = (const int*)d_in[5];
  const int* ed = (const int*)d_in[6];
  const float* Wc  =(const float*)d_in[7];  const float* bc  =(const float*)d_in[8];
  const float* gc  =(const float*)d_in[9];  const float* bec =(const float*)d_in[10];
  const float* Wca =(const float*)d_in[11]; const float* bca =(const float*)d_in[12];
  const float* Wex =(const float*)d_in[13]; const float* bex =(const float*)d_in[14];
  const float* gex =(const float*)d_in[15]; const float* beex=(const float*)d_in[16];
  const float* Wey =(const float*)d_in[17]; const float* bey =(const float*)d_in[18];
  const float* gey =(const float*)d_in[19]; const float* beey=(const float*)d_in[20];
  const float* We  =(const float*)d_in[21]; const float* be  =(const float*)d_in[22];

  float* outc = (float*)d_out;
  float* oute = outc + 524288;          // (B,L,R,H)
  float* outl = outc + 8912896;         // (B,L,L,FE)

  char* ws = (char*)d_ws;
  int* flags = (int*)ws;
  u16* wpc = (u16*)(ws + 4096);         // 147456 B
  u16* wpx = (u16*)(ws + 151552);       // 131072 B
  u16* wpy = (u16*)(ws + 282624);       // 131072 B
  u16* wpe = (u16*)(ws + 413696);       //  65536 B
  u16* xf  = (u16*)(ws + 479232);       // 1 MB bf16
  u16* yf  = (u16*)(ws + 1527808);      // 4 MB bf16 (ends ~5.5 MB)

  hipLaunchKernelGGL(k_prepack, dim3(288), dim3(256), 0, stream,
                     Wc, Wca, Wex, Wey, We, (const unsigned char*)mask,
                     wpc, wpx, wpy, wpe, flags);
  (void)hipMemsetAsync(outl, 0, (size_t)16777216*4, stream);
  hipLaunchKernelGGL(k_nl, dim3(16), dim3(256), 0, stream, lig, wpx, bex, gex, beex, xf);
  hipLaunchKernelGGL(k_nl, dim3(64), dim3(256), 0, stream, rec, wpy, bey, gey, beey, yf);
  hipLaunchKernelGGL(k_contract, dim3(2048), dim3(256), 0, stream,
                     ll, mask, wpc, bc, bca, gc, bec, flags, outc);
  hipLaunchKernelGGL(k_expand, dim3(256), dim3(256), 0, stream, xf, yf, oute);
  hipLaunchKernelGGL(k_edges, dim3(256), dim3(128), 0, stream, lig, eb, es, ed, wpe, be, outl);
}

// Round 2
// 533.391 us; speedup vs baseline: 1.2647x; 1.0507x over previous
//
#include <hip/hip_runtime.h>
#include <cstdint>
#include <cstddef>

typedef unsigned int u32;
typedef unsigned short u16;
typedef __bf16 bf16x8 __attribute__((ext_vector_type(8)));
typedef float f32x16 __attribute__((ext_vector_type(16)));
typedef float f32x4v __attribute__((ext_vector_type(4)));

#define DEV static __device__ __forceinline__

DEV u16 f2bf(float f){ u32 u=__float_as_uint(f); return (u16)((u + 0x7FFFu + ((u>>16)&1u))>>16); }
DEV uint2 cvt4(float4 v){
  uint2 r;
  r.x = (u32)f2bf(v.x) | ((u32)f2bf(v.y)<<16);
  r.y = (u32)f2bf(v.z) | ((u32)f2bf(v.w)<<16);
  return r;
}
DEV uint2 cvt4(f32x4v v){
  uint2 r;
  r.x = (u32)f2bf(v.x) | ((u32)f2bf(v.y)<<16);
  r.y = (u32)f2bf(v.z) | ((u32)f2bf(v.w)<<16);
  return r;
}
DEV u32 lrelu_pk(u32 u){
  float lo=__uint_as_float(u<<16);
  float hi=__uint_as_float(u&0xFFFF0000u);
  lo=fmaxf(lo,0.01f*lo); hi=fmaxf(hi,0.01f*hi);
  return (u32)f2bf(lo) | (((u32)f2bf(hi))<<16);
}

// ---------------------------------------------------------------------------
// Pre-pack f32 weights into bf16 MFMA B-fragment order + detect mask dtype.
// B-frag (32x32x16): n = lane&31, k = kk*16 + (lane>>5)*8 + j
// ---------------------------------------------------------------------------
__global__ void k_prepack(const float* __restrict__ Wc, const float* __restrict__ Wca,
    const float* __restrict__ Wex, const float* __restrict__ Wey, const float* __restrict__ We,
    const unsigned char* __restrict__ maskb,
    u16* __restrict__ wpc, u16* __restrict__ wpx, u16* __restrict__ wpy,
    u16* __restrict__ wpe, int* __restrict__ flags)
{
  int idx = blockIdx.x*256 + threadIdx.x;
  {
    int t=idx>>13, kk=(idx>>9)&15, ln=(idx>>3)&63, j=idx&7;
    int n=t*32+(ln&31), k=kk*16+(ln>>5)*8+j;
    if (idx < 73728){           // Wc (256 out) + Wca (8 out) + zero-pad -> 9 tiles
      float v;
      if (t<8) v = Wc[n*256+k];
      else { int n2=n-256; v = (n2<8) ? Wca[n2*256+k] : 0.f; }
      wpc[idx]=f2bf(v);
    }
    if (idx < 65536){ wpx[idx]=f2bf(Wex[n*256+k]); wpy[idx]=f2bf(Wey[n*256+k]); }
  }
  if (idx < 32768){             // We: K=512 -> 32 kk, 2 tiles
    int t=idx>>14, kk=(idx>>9)&31, ln=(idx>>3)&63, j=idx&7;
    int n=t*32+(ln&31), k=kk*16+(ln>>5)*8+j;
    wpe[idx]=f2bf(We[n*512+k]);
  }
  if (idx==0){                  // mask dtype sniffer (~90% ones)
    int c3f1=0,c3f3=0,nzoff=0,nz4m8=0,nz0=0;
    for (int i=0;i<256;i++){
      unsigned char b=maskb[i];
      if ((i&3)==1 && b==0x3F) c3f1++;
      if ((i&3)==3 && b==0x3F) c3f3++;
      if ((i&3)!=0 && b) nzoff++;
      if ((i&7)>=4 && b) nz4m8++;
      if ((i&7)==0 && b) nz0++;
    }
    int mode;
    if (c3f1>8) mode=2;                    // bf16
    else if (c3f3>8) mode=3;               // f32
    else if (nzoff>8) mode=0;              // bool / uint8
    else if (nz4m8==0 && nz0>4) mode=4;    // int64
    else mode=1;                           // int32
    flags[0]=mode;
  }
}

// ---------------------------------------------------------------------------
// AttentionContract: one workgroup per (b,l). f32 slab -> bf16 LDS (XOR
// swizzle on 16B granules), 9-tile 32x32x16 MFMA (tile 8 = Wca logits),
// LN in-register, masked softmax over y, weighted contraction.
// Round-2: depth-1 software pipeline — prefetch next-kk A ds_read + all 9
// weight fragments before the current MFMA cluster (one rolling vmcnt wait
// per kk, covered by 9 MFMAs + 2-block TLP). VGPRs are free: LDS caps us at
// 2 blocks/CU, so up to ~1024 regs/wave available.
// ---------------------------------------------------------------------------
__global__ __launch_bounds__(256,2) void k_contract(
    const float* __restrict__ ll, const void* __restrict__ maskp,
    const u16* __restrict__ Wp, const float* __restrict__ bc, const float* __restrict__ bca,
    const float* __restrict__ gc, const float* __restrict__ bec,
    const int* __restrict__ flags, float* __restrict__ outc)
{
  __shared__ __attribute__((aligned(16))) union SMem {
    char slab[65536];                       // 128 rows * 512B bf16
    struct { float logit[1536]; float partial[1024]; } post;
  } sm;
  __shared__ float maskv[128];

  int tid=threadIdx.x, lane=tid&63, wave=tid>>6;
  int bl = blockIdx.x;
  const float* src = ll + (size_t)bl*(128*256);

  if (tid < 128){
    int mode = flags[0];
    size_t mi = (size_t)bl*128 + tid;
    bool on;
    if (mode==0)      on = ((const unsigned char*)maskp)[mi] != 0;
    else if (mode==1) on = ((const int*)maskp)[mi] != 0;
    else if (mode==2) on = ((const u16*)maskp)[mi] != 0;
    else if (mode==4) on = ((const unsigned long long*)maskp)[mi] != 0ull;
    else              on = (((const u32*)maskp)[mi]<<1) != 0;
    maskv[tid] = on ? 1.f : 0.f;
  }

  // stage: wave w rows [w*32, w*32+32); lane covers f32 cols [lane*4, +4)
  // nt loads: streaming data, keep L1/L2 for the weight working set.
  #pragma unroll 8
  for (int it=0;it<32;it++){
    int row = wave*32 + it;
    f32x4v v = __builtin_nontemporal_load((const f32x4v*)(src + row*256 + lane*4));
    uint2 pk = cvt4(v);
    *(uint2*)(sm.slab + row*512 + ((((lane>>1) ^ (row&31)))<<4) + (lane&1)*8) = pk;
  }
  __syncthreads();

  f32x16 acc[9];
  #pragma unroll
  for (int t=0;t<9;t++)
    #pragma unroll
    for (int i=0;i<16;i++) acc[t][i]=0.f;
  int y0 = wave*32;
  int arow = y0 + (lane&31);
  int axor = arow & 31;
  int half = lane>>5;
  const char* sb = sm.slab;
  const u16* wl = Wp + lane*8;

  // pipeline prologue: kk=0 fragments
  uint4 raw = *(const uint4*)(sb + arow*512 + ((half ^ axor)<<4));
  bf16x8 w0 = *(const bf16x8*)(wl);
  bf16x8 w1 = *(const bf16x8*)(wl + 8192);
  bf16x8 w2 = *(const bf16x8*)(wl + 16384);
  bf16x8 w3 = *(const bf16x8*)(wl + 24576);
  bf16x8 w4 = *(const bf16x8*)(wl + 32768);
  bf16x8 w5 = *(const bf16x8*)(wl + 40960);
  bf16x8 w6 = *(const bf16x8*)(wl + 49152);
  bf16x8 w7 = *(const bf16x8*)(wl + 57344);
  bf16x8 w8 = *(const bf16x8*)(wl + 65536);

  #pragma unroll 4
  for (int kk=0;kk<16;kk++){
    int kn = (kk+1)&15;                      // wrap: last iter re-loads kk=0 (harmless)
    uint4 rawn = *(const uint4*)(sb + arow*512 + (((kn*2+half) ^ axor)<<4));
    const u16* wkn = wl + (size_t)kn*512;
    bf16x8 n0 = *(const bf16x8*)(wkn);
    bf16x8 n1 = *(const bf16x8*)(wkn + 8192);
    bf16x8 n2 = *(const bf16x8*)(wkn + 16384);
    bf16x8 n3 = *(const bf16x8*)(wkn + 24576);
    bf16x8 n4 = *(const bf16x8*)(wkn + 32768);
    bf16x8 n5 = *(const bf16x8*)(wkn + 40960);
    bf16x8 n6 = *(const bf16x8*)(wkn + 49152);
    bf16x8 n7 = *(const bf16x8*)(wkn + 57344);
    bf16x8 n8 = *(const bf16x8*)(wkn + 65536);
    __builtin_amdgcn_sched_barrier(0);       // pin prefetch issue before MFMA cluster
    uint4 t4; t4.x=lrelu_pk(raw.x); t4.y=lrelu_pk(raw.y); t4.z=lrelu_pk(raw.z); t4.w=lrelu_pk(raw.w);
    bf16x8 a = __builtin_bit_cast(bf16x8, t4);
    acc[0] = __builtin_amdgcn_mfma_f32_32x32x16_bf16(a, w0, acc[0], 0,0,0);
    acc[1] = __builtin_amdgcn_mfma_f32_32x32x16_bf16(a, w1, acc[1], 0,0,0);
    acc[2] = __builtin_amdgcn_mfma_f32_32x32x16_bf16(a, w2, acc[2], 0,0,0);
    acc[3] = __builtin_amdgcn_mfma_f32_32x32x16_bf16(a, w3, acc[3], 0,0,0);
    acc[4] = __builtin_amdgcn_mfma_f32_32x32x16_bf16(a, w4, acc[4], 0,0,0);
    acc[5] = __builtin_amdgcn_mfma_f32_32x32x16_bf16(a, w5, acc[5], 0,0,0);
    acc[6] = __builtin_amdgcn_mfma_f32_32x32x16_bf16(a, w6, acc[6], 0,0,0);
    acc[7] = __builtin_amdgcn_mfma_f32_32x32x16_bf16(a, w7, acc[7], 0,0,0);
    acc[8] = __builtin_amdgcn_mfma_f32_32x32x16_bf16(a, w8, acc[8], 0,0,0);
    raw=rawn;
    w0=n0; w1=n1; w2=n2; w3=n3; w4=n4; w5=n5; w6=n6; w7=n7; w8=n8;
  }
  __syncthreads();   // slab reads done; logit/partial overlay becomes live

  int col = lane & 31;
  float bv[8], gv[8], bev[8];
  #pragma unroll
  for (int t=0;t<8;t++){
    int n=t*32+col; bv[t]=bc[n]; gv[t]=gc[n]; bev[t]=bec[n];
  }
  float bcav = (col<8) ? bca[col] : 0.f;

  #pragma unroll
  for (int r=0;r<16;r++){
    int row=(r&3)+8*(r>>2)+4*half;
    float s=0.f, sq=0.f;
    #pragma unroll
    for (int t=0;t<8;t++){
      float v = acc[t][r] + bv[t]; acc[t][r]=v; s += v; sq = fmaf(v,v,sq);
    }
    #pragma unroll
    for (int m=1;m<=16;m<<=1){ s += __shfl_xor(s,m,64); sq += __shfl_xor(sq,m,64); }
    float mu = s*(1.f/256.f);
    float var = fmaf(sq,1.f/256.f, -mu*mu);
    float rin = rsqrtf(var+1e-5f);
    #pragma unroll
    for (int t=0;t<8;t++) acc[t][r] = fmaf((acc[t][r]-mu)*rin, gv[t], bev[t]);
    if (col<8) sm.post.logit[(y0+row)*12+col] = acc[8][r] + bcav;
  }
  __syncthreads();

  // masked softmax over y (len 128): 32 threads per head
  {
    int h = tid>>5, sub = tid&31;
    float lv[4], ev[4];
    #pragma unroll
    for (int j=0;j<4;j++) lv[j] = sm.post.logit[(sub+32*j)*12 + h];
    float mx = fmaxf(fmaxf(lv[0],lv[1]), fmaxf(lv[2],lv[3]));
    #pragma unroll
    for (int m=1;m<=16;m<<=1) mx = fmaxf(mx, __shfl_xor(mx,m,64));
    float ssum=0.f;
    #pragma unroll
    for (int j=0;j<4;j++){ ev[j] = __expf(lv[j]-mx)*maskv[sub+32*j]; ssum += ev[j]; }
    #pragma unroll
    for (int m=1;m<=16;m<<=1) ssum += __shfl_xor(ssum,m,64);
    float inv = 1.f/(ssum+1e-10f);
    #pragma unroll
    for (int j=0;j<4;j++) sm.post.logit[(sub+32*j)*12+h] = ev[j]*inv;
  }
  __syncthreads();

  // contraction: sum_y w[y,h] * of[y,n]
  float ctr[8];
  #pragma unroll
  for (int t=0;t<8;t++) ctr[t]=0.f;
  #pragma unroll
  for (int r=0;r<16;r++){
    int row=(r&3)+8*(r>>2)+4*half;
    const float* wr = &sm.post.logit[(y0+row)*12];
    float4 w0v = *(const float4*)wr;
    float4 w1v = *(const float4*)(wr+4);
    ctr[0]=fmaf(w0v.x,acc[0][r],ctr[0]); ctr[1]=fmaf(w0v.y,acc[1][r],ctr[1]);
    ctr[2]=fmaf(w0v.z,acc[2][r],ctr[2]); ctr[3]=fmaf(w0v.w,acc[3][r],ctr[3]);
    ctr[4]=fmaf(w1v.x,acc[4][r],ctr[4]); ctr[5]=fmaf(w1v.y,acc[5][r],ctr[5]);
    ctr[6]=fmaf(w1v.z,acc[6][r],ctr[6]); ctr[7]=fmaf(w1v.w,acc[7][r],ctr[7]);
  }
  #pragma unroll
  for (int t=0;t<8;t++) ctr[t] += __shfl_xor(ctr[t],32,64);
  if (lane<32){
    #pragma unroll
    for (int t=0;t<8;t++) sm.post.partial[wave*256 + t*32 + col] = ctr[t];
  }
  __syncthreads();
  float v = sm.post.partial[tid]+sm.post.partial[256+tid]
          + sm.post.partial[512+tid]+sm.post.partial[768+tid];
  outc[(size_t)bl*256 + tid] = v;
}

// ---------------------------------------------------------------------------
// NormAndLinear for lig_feat (blocks 0..15 -> xf) and rec_feat (16..79 -> yf)
// in one launch. Same depth-1 pipelined kk loop as k_contract.
// ---------------------------------------------------------------------------
__global__ __launch_bounds__(256,2) void k_nl(
    const float* __restrict__ lig, const float* __restrict__ rec,
    const u16* __restrict__ Wpx, const u16* __restrict__ Wpy,
    const float* __restrict__ bx, const float* __restrict__ gx, const float* __restrict__ ex,
    const float* __restrict__ by, const float* __restrict__ gy, const float* __restrict__ ey,
    u16* __restrict__ xf, u16* __restrict__ yf)
{
  __shared__ __attribute__((aligned(16))) char slab[65536];
  int tid=threadIdx.x, lane=tid&63, wave=tid>>6;
  bool isx = blockIdx.x < 16;
  int bb = isx ? blockIdx.x : blockIdx.x - 16;
  const float* src  = isx ? lig : rec;
  const u16*  Wp    = isx ? Wpx : Wpy;
  const float* bias = isx ? bx : by;
  const float* g    = isx ? gx : gy;
  const float* beta = isx ? ex : ey;
  u16* dst          = isx ? xf : yf;

  const float* s0 = src + (size_t)bb*(128*256);
  #pragma unroll 8
  for (int it=0;it<32;it++){
    int row = wave*32 + it;
    float4 v = *(const float4*)(s0 + row*256 + lane*4);
    uint2 pk = cvt4(v);
    *(uint2*)(slab + row*512 + ((((lane>>1) ^ (row&31)))<<4) + (lane&1)*8) = pk;
  }
  __syncthreads();

  f32x16 acc[8];
  #pragma unroll
  for (int t=0;t<8;t++)
    #pragma unroll
    for (int i=0;i<16;i++) acc[t][i]=0.f;
  int y0 = wave*32;
  int arow = y0 + (lane&31);
  int axor = arow & 31;
  int half = lane>>5;
  const u16* wl = Wp + lane*8;

  uint4 raw = *(const uint4*)(slab + arow*512 + ((half ^ axor)<<4));
  bf16x8 w0 = *(const bf16x8*)(wl);
  bf16x8 w1 = *(const bf16x8*)(wl + 8192);
  bf16x8 w2 = *(const bf16x8*)(wl + 16384);
  bf16x8 w3 = *(const bf16x8*)(wl + 24576);
  bf16x8 w4 = *(const bf16x8*)(wl + 32768);
  bf16x8 w5 = *(const bf16x8*)(wl + 40960);
  bf16x8 w6 = *(const bf16x8*)(wl + 49152);
  bf16x8 w7 = *(const bf16x8*)(wl + 57344);

  #pragma unroll 4
  for (int kk=0;kk<16;kk++){
    int kn = (kk+1)&15;
    uint4 rawn = *(const uint4*)(slab + arow*512 + (((kn*2+half) ^ axor)<<4));
    const u16* wkn = wl + (size_t)kn*512;
    bf16x8 n0 = *(const bf16x8*)(wkn);
    bf16x8 n1 = *(const bf16x8*)(wkn + 8192);
    bf16x8 n2 = *(const bf16x8*)(wkn + 16384);
    bf16x8 n3 = *(const bf16x8*)(wkn + 24576);
    bf16x8 n4 = *(const bf16x8*)(wkn + 32768);
    bf16x8 n5 = *(const bf16x8*)(wkn + 40960);
    bf16x8 n6 = *(const bf16x8*)(wkn + 49152);
    bf16x8 n7 = *(const bf16x8*)(wkn + 57344);
    __builtin_amdgcn_sched_barrier(0);
    uint4 t4; t4.x=lrelu_pk(raw.x); t4.y=lrelu_pk(raw.y); t4.z=lrelu_pk(raw.z); t4.w=lrelu_pk(raw.w);
    bf16x8 a = __builtin_bit_cast(bf16x8, t4);
    acc[0] = __builtin_amdgcn_mfma_f32_32x32x16_bf16(a, w0, acc[0], 0,0,0);
    acc[1] = __builtin_amdgcn_mfma_f32_32x32x16_bf16(a, w1, acc[1], 0,0,0);
    acc[2] = __builtin_amdgcn_mfma_f32_32x32x16_bf16(a, w2, acc[2], 0,0,0);
    acc[3] = __builtin_amdgcn_mfma_f32_32x32x16_bf16(a, w3, acc[3], 0,0,0);
    acc[4] = __builtin_amdgcn_mfma_f32_32x32x16_bf16(a, w4, acc[4], 0,0,0);
    acc[5] = __builtin_amdgcn_mfma_f32_32x32x16_bf16(a, w5, acc[5], 0,0,0);
    acc[6] = __builtin_amdgcn_mfma_f32_32x32x16_bf16(a, w6, acc[6], 0,0,0);
    acc[7] = __builtin_amdgcn_mfma_f32_32x32x16_bf16(a, w7, acc[7], 0,0,0);
    raw=rawn;
    w0=n0; w1=n1; w2=n2; w3=n3; w4=n4; w5=n5; w6=n6; w7=n7;
  }
  int col = lane & 31;
  float bv[8], gv[8], bev[8];
  #pragma unroll
  for (int t=0;t<8;t++){
    int n=t*32+col; bv[t]=bias[n]; gv[t]=g[n]; bev[t]=beta[n];
  }
  #pragma unroll
  for (int r=0;r<16;r++){
    int row=(r&3)+8*(r>>2)+4*half;
    float s=0.f, sq=0.f;
    #pragma unroll
    for (int t=0;t<8;t++){
      float v = acc[t][r] + bv[t]; acc[t][r]=v; s += v; sq = fmaf(v,v,sq);
    }
    #pragma unroll
    for (int m=1;m<=16;m<<=1){ s += __shfl_xor(s,m,64); sq += __shfl_xor(sq,m,64); }
    float mu = s*(1.f/256.f);
    float var = fmaf(sq,1.f/256.f, -mu*mu);
    float rin = rsqrtf(var+1e-5f);
    size_t rowg = (size_t)bb*128 + y0 + row;
    #pragma unroll
    for (int t=0;t<8;t++){
      float v = fmaf((acc[t][r]-mu)*rin, gv[t], bev[t]);
      dst[rowg*256 + t*32 + col] = f2bf(v);
    }
  }
}

// ---------------------------------------------------------------------------
// AttentionExpand: per (b, 32-y tile): C[x,y,h] = sum_f xf[x,h,f]*yf[y,h,f]
// 16x16x32 MFMA, LDS transpose, f32 output.
// Round-2: stage is per-wave -> inner __syncthreads removed (wave-order +
// lgkmcnt suffice); 8 h-MFMAs accumulated in regs then staged via vectorized
// float4 stores (was 32 scalar stores into 4 banks).
// ---------------------------------------------------------------------------
__global__ __launch_bounds__(256,2) void k_expand(
    const u16* __restrict__ xf, const u16* __restrict__ yf, float* __restrict__ oute)
{
  __shared__ __attribute__((aligned(16))) u16 ytile[32*264];
  __shared__ __attribute__((aligned(16))) float stage[4][2048];
  int tid=threadIdx.x, lane=tid&63, wave=tid>>6;
  int bi = blockIdx.x>>4, yt = blockIdx.x&15;

  #pragma unroll
  for (int i=0;i<4;i++){
    int idx=i*256+tid; int row=idx>>5, c=idx&31;
    uint4 v = *(const uint4*)(yf + ((size_t)(bi*512 + yt*32 + row))*256 + c*8);
    *(uint4*)((char*)ytile + row*528 + c*16) = v;
  }
  __syncthreads();

  bf16x8 af[2][8];
  #pragma unroll
  for (int xi=0;xi<2;xi++){
    int x = (wave*2+xi)*16 + (lane&15);
    #pragma unroll
    for (int h=0;h<8;h++)
      af[xi][h] = *(const bf16x8*)(xf + ((size_t)(bi*128+x))*256 + h*32 + (lane>>4)*8);
  }
  float* stw = stage[wave];
  #pragma unroll
  for (int xi=0;xi<2;xi++){
    #pragma unroll
    for (int nt=0;nt<2;nt++){
      f32x4v c[8];
      #pragma unroll
      for (int h=0;h<8;h++){
        bf16x8 bv = *(const bf16x8*)((const char*)ytile + (nt*16+(lane&15))*528 + (h*32+(lane>>4)*8)*2);
        f32x4v z = {0.f,0.f,0.f,0.f};
        c[h] = __builtin_amdgcn_mfma_f32_16x16x32_bf16(af[xi][h], bv, z, 0,0,0);
      }
      #pragma unroll
      for (int q=0;q<4;q++){
        int xp=(lane>>4)*4+q, yp=lane&15;
        float* sp = &stw[(xp*16+yp)*8];
        float4 v0; v0.x=c[0][q]; v0.y=c[1][q]; v0.z=c[2][q]; v0.w=c[3][q];
        float4 v1; v1.x=c[4][q]; v1.y=c[5][q]; v1.z=c[6][q]; v1.w=c[7][q];
        *(float4*)sp = v0;
        *(float4*)(sp+4) = v1;
      }
      // per-wave stage: no barrier needed (wave-order + lgkmcnt)
      #pragma unroll
      for (int j=0;j<4;j++){
        int pi=j*64+lane, xp=pi>>4, yp=pi&15;
        const float* sp = &stw[(xp*16+yp)*8];
        float4 a = *(const float4*)sp;
        float4 b2 = *(const float4*)(sp+4);
        size_t x=(size_t)(wave*2+xi)*16+xp, y=(size_t)yt*32+nt*16+yp;
        float* po = oute + (((size_t)bi*128+x)*512 + y)*8;
        *(float4*)po = a;
        *(float4*)(po+4) = b2;
      }
    }
  }
}

// ---------------------------------------------------------------------------
// Edges: gather 64 edges' concat rows -> bf16 LDS (XOR swizzle, 64 granules),
// 32x32x16 MFMA K=512 (2 waves), bias+lrelu, f32 atomicAdd scatter.
// Round-2: depth-1 pipelined kk loop (prefetch next A ds_reads + weights).
// ---------------------------------------------------------------------------
__global__ __launch_bounds__(128,1) void k_edges(
    const float* __restrict__ lig, const int* __restrict__ eb, const int* __restrict__ es,
    const int* __restrict__ ed, const u16* __restrict__ Wp, const float* __restrict__ bias,
    float* __restrict__ outl)
{
  __shared__ __attribute__((aligned(16))) char slab[65536];  // 64 edges * 1024B
  int tid=threadIdx.x, lane=tid&63, wave=tid>>6;  // 2 waves
  int e0 = blockIdx.x*64;
  int ge = e0 + wave*32 + (lane&31);
  int b0=eb[ge], s0=es[ge], d0=ed[ge];
  long long ps = (long long)(uintptr_t)(lig + ((size_t)(b0*128+s0))*256);
  long long pd = (long long)(uintptr_t)(lig + ((size_t)(b0*128+d0))*256);
  #pragma unroll 4
  for (int i=0;i<32;i++){
    int ri = wave*32 + i;
    const float* sp = (const float*)(uintptr_t)__shfl(ps, i, 32);
    const float* dp = (const float*)(uintptr_t)__shfl(pd, i, 32);
    #pragma unroll
    for (int j=0;j<2;j++){
      const float* base = j ? dp : sp;
      float4 v = *(const float4*)(base + lane*4);
      uint2 pk = cvt4(v);
      int g = j*32 + (lane>>1);
      *(uint2*)(slab + (size_t)ri*1024 + ((g ^ (ri&63))<<4) + (lane&1)*8) = pk;
    }
  }
  __syncthreads();

  f32x16 acc[2];
  #pragma unroll
  for (int t=0;t<2;t++)
    #pragma unroll
    for (int i=0;i<16;i++) acc[t][i]=0.f;
  int arow = wave*32 + (lane&31);
  int axor = arow & 63;
  int half = lane>>5;
  const u16* wl = Wp + lane*8;

  uint4 raw0 = *(const uint4*)(slab + (size_t)arow*1024 + ((half ^ axor)<<4));
  uint4 raw1 = *(const uint4*)(slab + (size_t)arow*1024 + (((2+half) ^ axor)<<4));
  bf16x8 b00 = *(const bf16x8*)(wl);
  bf16x8 b01 = *(const bf16x8*)(wl + 16384);
  bf16x8 b10 = *(const bf16x8*)(wl + 512);
  bf16x8 b11 = *(const bf16x8*)(wl + 16896);

  for (int kk=0;kk<32;kk+=2){
    int kn = (kk+2)&31;
    uint4 r0n = *(const uint4*)(slab + (size_t)arow*1024 + (((kn*2+half) ^ axor)<<4));
    uint4 r1n = *(const uint4*)(slab + (size_t)arow*1024 + ((((kn+1)*2+half) ^ axor)<<4));
    const u16* wkn = wl + (size_t)kn*512;
    bf16x8 n00 = *(const bf16x8*)(wkn);
    bf16x8 n01 = *(const bf16x8*)(wkn + 16384);
    bf16x8 n10 = *(const bf16x8*)(wkn + 512);
    bf16x8 n11 = *(const bf16x8*)(wkn + 16896);
    __builtin_amdgcn_sched_barrier(0);
    bf16x8 a0 = __builtin_bit_cast(bf16x8, raw0);   // lrelu is AFTER linear here
    bf16x8 a1 = __builtin_bit_cast(bf16x8, raw1);
    acc[0] = __builtin_amdgcn_mfma_f32_32x32x16_bf16(a0, b00, acc[0], 0,0,0);
    acc[1] = __builtin_amdgcn_mfma_f32_32x32x16_bf16(a0, b01, acc[1], 0,0,0);
    acc[0] = __builtin_amdgcn_mfma_f32_32x32x16_bf16(a1, b10, acc[0], 0,0,0);
    acc[1] = __builtin_amdgcn_mfma_f32_32x32x16_bf16(a1, b11, acc[1], 0,0,0);
    raw0=r0n; raw1=r1n;
    b00=n00; b01=n01; b10=n10; b11=n11;
  }
  int col = lane&31;
  float bv0=bias[col], bv1=bias[32+col];
  #pragma unroll
  for (int r=0;r<16;r++){
    int row=(r&3)+8*(r>>2)+4*half;
    int ee = e0 + wave*32 + row;
    int bb=eb[ee], ss=es[ee], dd=ed[ee];
    float* cell = outl + (((size_t)(bb*128+ss))*128 + (size_t)dd)*64;
    #pragma unroll
    for (int t=0;t<2;t++){
      float v = acc[t][r] + (t ? bv1 : bv0);
      v = fmaxf(v, 0.01f*v);
      atomicAdd(cell + t*32 + col, v);
    }
  }
}

// ---------------------------------------------------------------------------
extern "C" void kernel_launch(void* const* d_in, const int* in_sizes, int n_in,
                              void* d_out, int out_size, void* d_ws, size_t ws_size,
                              hipStream_t stream)
{
  (void)in_sizes; (void)n_in; (void)out_size; (void)ws_size;
  const float* ll  = (const float*)d_in[0];
  const float* lig = (const float*)d_in[1];
  const float* rec = (const float*)d_in[2];
  const void* mask = d_in[3];
  const int* eb = (const int*)d_in[4];
  const int* es = (const int*)d_in[5];
  const int* ed = (const int*)d_in[6];
  const float* Wc  =(const float*)d_in[7];  const float* bc  =(const float*)d_in[8];
  const float* gc  =(const float*)d_in[9];  const float* bec =(const float*)d_in[10];
  const float* Wca =(const float*)d_in[11]; const float* bca =(const float*)d_in[12];
  const float* Wex =(const float*)d_in[13]; const float* bex =(const float*)d_in[14];
  const float* gex =(const float*)d_in[15]; const float* beex=(const float*)d_in[16];
  const float* Wey =(const float*)d_in[17]; const float* bey =(const float*)d_in[18];
  const float* gey =(const float*)d_in[19]; const float* beey=(const float*)d_in[20];
  const float* We  =(const float*)d_in[21]; const float* be  =(const float*)d_in[22];

  float* outc = (float*)d_out;
  float* oute = outc + 524288;          // (B,L,R,H)
  float* outl = outc + 8912896;         // (B,L,L,FE)

  char* ws = (char*)d_ws;
  int* flags = (int*)ws;
  u16* wpc = (u16*)(ws + 4096);         // 147456 B
  u16* wpx = (u16*)(ws + 151552);       // 131072 B
  u16* wpy = (u16*)(ws + 282624);       // 131072 B
  u16* wpe = (u16*)(ws + 413696);       //  65536 B
  u16* xf  = (u16*)(ws + 479232);       // 1 MB bf16
  u16* yf  = (u16*)(ws + 1527808);      // 4 MB bf16 (ends ~5.5 MB)

  hipLaunchKernelGGL(k_prepack, dim3(288), dim3(256), 0, stream,
                     Wc, Wca, Wex, Wey, We, (const unsigned char*)mask,
                     wpc, wpx, wpy, wpe, flags);
  (void)hipMemsetAsync(outl, 0, (size_t)16777216*4, stream);
  hipLaunchKernelGGL(k_nl, dim3(80), dim3(256), 0, stream,
                     lig, rec, wpx, wpy, bex, gex, beex, bey, gey, beey, xf, yf);
  hipLaunchKernelGGL(k_contract, dim3(2048), dim3(256), 0, stream,
                     ll, mask, wpc, bc, bca, gc, bec, flags, outc);
  hipLaunchKernelGGL(k_expand, dim3(256), dim3(256), 0, stream, xf, yf, oute);
  hipLaunchKernelGGL(k_edges, dim3(256), dim3(128), 0, stream, lig, eb, es, ed, wpe, be, outl);
}

// Round 3
// 503.925 us; speedup vs baseline: 1.3386x; 1.0585x over previous
//
#include <hip/hip_runtime.h>
#include <cstdint>
#include <cstddef>

typedef unsigned int u32;
typedef unsigned short u16;
typedef __bf16 bf16x8 __attribute__((ext_vector_type(8)));
typedef float f32x16 __attribute__((ext_vector_type(16)));
typedef float f32x4v __attribute__((ext_vector_type(4)));

#define DEV static __device__ __forceinline__

DEV u16 f2bf(float f){ u32 u=__float_as_uint(f); return (u16)((u + 0x7FFFu + ((u>>16)&1u))>>16); }
// single-instruction RNE pack of 2 f32 -> 2 bf16 (no builtin on gfx950; asm)
DEV u32 cvtpk(float lo, float hi){ u32 r; asm("v_cvt_pk_bf16_f32 %0, %1, %2":"=v"(r):"v"(lo),"v"(hi)); return r; }
DEV uint2 cvt4(float4 v){ uint2 r; r.x=cvtpk(v.x,v.y); r.y=cvtpk(v.z,v.w); return r; }
DEV uint2 cvt4(f32x4v v){ uint2 r; r.x=cvtpk(v.x,v.y); r.y=cvtpk(v.z,v.w); return r; }
DEV u32 lrelu_pk(u32 u){
  float lo=__uint_as_float(u<<16);
  float hi=__uint_as_float(u&0xFFFF0000u);
  lo=fmaxf(lo,0.01f*lo); hi=fmaxf(hi,0.01f*hi);
  return cvtpk(lo,hi);
}

// ---------------------------------------------------------------------------
// Pre-pack f32 weights into bf16 MFMA B-fragment order + detect mask dtype
// + zero outl (replaces separate hipMemsetAsync fill dispatch).
// B-frag (32x32x16): n = lane&31, k = kk*16 + (lane>>5)*8 + j
// ---------------------------------------------------------------------------
__global__ void k_prepack(const float* __restrict__ Wc, const float* __restrict__ Wca,
    const float* __restrict__ Wex, const float* __restrict__ Wey, const float* __restrict__ We,
    const unsigned char* __restrict__ maskb,
    u16* __restrict__ wpc, u16* __restrict__ wpx, u16* __restrict__ wpy,
    u16* __restrict__ wpe, int* __restrict__ flags, float* __restrict__ outl)
{
  int idx = blockIdx.x*256 + threadIdx.x;
  {
    int t=idx>>13, kk=(idx>>9)&15, ln=(idx>>3)&63, j=idx&7;
    int n=t*32+(ln&31), k=kk*16+(ln>>5)*8+j;
    if (idx < 73728){           // Wc (256 out) + Wca (8 out) + zero-pad -> 9 tiles
      float v;
      if (t<8) v = Wc[n*256+k];
      else { int n2=n-256; v = (n2<8) ? Wca[n2*256+k] : 0.f; }
      wpc[idx]=f2bf(v);
    }
    if (idx < 65536){ wpx[idx]=f2bf(Wex[n*256+k]); wpy[idx]=f2bf(Wey[n*256+k]); }
  }
  if (idx < 32768){             // We: K=512 -> 32 kk, 2 tiles
    int t=idx>>14, kk=(idx>>9)&31, ln=(idx>>3)&63, j=idx&7;
    int n=t*32+(ln&31), k=kk*16+(ln>>5)*8+j;
    wpe[idx]=f2bf(We[n*512+k]);
  }
  // grid-stride zero of outl: 16.7M floats = 4.19M float4
  {
    float4 z; z.x=0.f; z.y=0.f; z.z=0.f; z.w=0.f;
    float4* p = (float4*)outl;
    for (size_t i = (size_t)idx; i < 4194304u; i += 73728u) p[i] = z;
  }
  if (idx==0){                  // mask dtype sniffer (~90% ones)
    int c3f1=0,c3f3=0,nzoff=0,nz4m8=0,nz0=0;
    for (int i=0;i<256;i++){
      unsigned char b=maskb[i];
      if ((i&3)==1 && b==0x3F) c3f1++;
      if ((i&3)==3 && b==0x3F) c3f3++;
      if ((i&3)!=0 && b) nzoff++;
      if ((i&7)>=4 && b) nz4m8++;
      if ((i&7)==0 && b) nz0++;
    }
    int mode;
    if (c3f1>8) mode=2;                    // bf16
    else if (c3f3>8) mode=3;               // f32
    else if (nzoff>8) mode=0;              // bool / uint8
    else if (nz4m8==0 && nz0>4) mode=4;    // int64
    else mode=1;                           // int32
    flags[0]=mode;
  }
}

// ---------------------------------------------------------------------------
// Shared LDS union for the fused kernel's three block roles.
// ---------------------------------------------------------------------------
union FMem {
  struct { char slab[65536]; float maskv[128]; } c;     // contract: 66048 B
  struct { u16 ytile[8448]; float stage[4][2048]; } e;  // expand:   49664 B
  char eslab[65536];                                    // edges:    65536 B
};

// ---------------------------------------------------------------------------
// Contract body: one block per (b,l). f32 slab -> bf16 LDS (XOR swizzle),
// 9-tile 32x32x16 MFMA (tile 8 = Wca logits), depth-1 pipelined kk loop,
// LN in-register, masked softmax over y, weighted contraction.
// ---------------------------------------------------------------------------
DEV void contract_body(FMem& sm, int bl,
    const float* __restrict__ ll, const void* __restrict__ maskp,
    const u16* __restrict__ Wp, const float* __restrict__ bc, const float* __restrict__ bca,
    const float* __restrict__ gc, const float* __restrict__ bec,
    const int* __restrict__ flags, float* __restrict__ outc)
{
  int tid=threadIdx.x, lane=tid&63, wave=tid>>6;
  const float* src = ll + (size_t)bl*(128*256);

  if (tid < 128){
    int mode = flags[0];
    size_t mi = (size_t)bl*128 + tid;
    bool on;
    if (mode==0)      on = ((const unsigned char*)maskp)[mi] != 0;
    else if (mode==1) on = ((const int*)maskp)[mi] != 0;
    else if (mode==2) on = ((const u16*)maskp)[mi] != 0;
    else if (mode==4) on = ((const unsigned long long*)maskp)[mi] != 0ull;
    else              on = (((const u32*)maskp)[mi]<<1) != 0;
    sm.c.maskv[tid] = on ? 1.f : 0.f;
  }

  // stage: wave w rows [w*32, +32); nt loads keep weights resident in L2
  #pragma unroll 8
  for (int it=0;it<32;it++){
    int row = wave*32 + it;
    f32x4v v = __builtin_nontemporal_load((const f32x4v*)(src + row*256 + lane*4));
    uint2 pk = cvt4(v);
    *(uint2*)(sm.c.slab + row*512 + ((((lane>>1) ^ (row&31)))<<4) + (lane&1)*8) = pk;
  }
  __syncthreads();

  f32x16 acc[9];
  #pragma unroll
  for (int t=0;t<9;t++)
    #pragma unroll
    for (int i=0;i<16;i++) acc[t][i]=0.f;
  int y0 = wave*32;
  int arow = y0 + (lane&31);
  int axor = arow & 31;
  int half = lane>>5;
  const char* sb = sm.c.slab;
  const u16* wl = Wp + lane*8;

  uint4 raw = *(const uint4*)(sb + arow*512 + ((half ^ axor)<<4));
  bf16x8 w0 = *(const bf16x8*)(wl);
  bf16x8 w1 = *(const bf16x8*)(wl + 8192);
  bf16x8 w2 = *(const bf16x8*)(wl + 16384);
  bf16x8 w3 = *(const bf16x8*)(wl + 24576);
  bf16x8 w4 = *(const bf16x8*)(wl + 32768);
  bf16x8 w5 = *(const bf16x8*)(wl + 40960);
  bf16x8 w6 = *(const bf16x8*)(wl + 49152);
  bf16x8 w7 = *(const bf16x8*)(wl + 57344);
  bf16x8 w8 = *(const bf16x8*)(wl + 65536);

  #pragma unroll 4
  for (int kk=0;kk<16;kk++){
    int kn = (kk+1)&15;                      // wrap: last iter re-loads kk=0 (harmless)
    uint4 rawn = *(const uint4*)(sb + arow*512 + (((kn*2+half) ^ axor)<<4));
    const u16* wkn = wl + (size_t)kn*512;
    bf16x8 n0 = *(const bf16x8*)(wkn);
    bf16x8 n1 = *(const bf16x8*)(wkn + 8192);
    bf16x8 n2 = *(const bf16x8*)(wkn + 16384);
    bf16x8 n3 = *(const bf16x8*)(wkn + 24576);
    bf16x8 n4 = *(const bf16x8*)(wkn + 32768);
    bf16x8 n5 = *(const bf16x8*)(wkn + 40960);
    bf16x8 n6 = *(const bf16x8*)(wkn + 49152);
    bf16x8 n7 = *(const bf16x8*)(wkn + 57344);
    bf16x8 n8 = *(const bf16x8*)(wkn + 65536);
    __builtin_amdgcn_sched_barrier(0);       // pin prefetch issue before MFMA cluster
    uint4 t4; t4.x=lrelu_pk(raw.x); t4.y=lrelu_pk(raw.y); t4.z=lrelu_pk(raw.z); t4.w=lrelu_pk(raw.w);
    bf16x8 a = __builtin_bit_cast(bf16x8, t4);
    acc[0] = __builtin_amdgcn_mfma_f32_32x32x16_bf16(a, w0, acc[0], 0,0,0);
    acc[1] = __builtin_amdgcn_mfma_f32_32x32x16_bf16(a, w1, acc[1], 0,0,0);
    acc[2] = __builtin_amdgcn_mfma_f32_32x32x16_bf16(a, w2, acc[2], 0,0,0);
    acc[3] = __builtin_amdgcn_mfma_f32_32x32x16_bf16(a, w3, acc[3], 0,0,0);
    acc[4] = __builtin_amdgcn_mfma_f32_32x32x16_bf16(a, w4, acc[4], 0,0,0);
    acc[5] = __builtin_amdgcn_mfma_f32_32x32x16_bf16(a, w5, acc[5], 0,0,0);
    acc[6] = __builtin_amdgcn_mfma_f32_32x32x16_bf16(a, w6, acc[6], 0,0,0);
    acc[7] = __builtin_amdgcn_mfma_f32_32x32x16_bf16(a, w7, acc[7], 0,0,0);
    acc[8] = __builtin_amdgcn_mfma_f32_32x32x16_bf16(a, w8, acc[8], 0,0,0);
    raw=rawn;
    w0=n0; w1=n1; w2=n2; w3=n3; w4=n4; w5=n5; w6=n6; w7=n7; w8=n8;
  }
  __syncthreads();   // slab reads done; logit/partial overlay becomes live

  float* logit = (float*)sm.c.slab;          // overlay: 1536 floats
  float* partial = logit + 1536;             // 1024 floats

  int col = lane & 31;
  float bv[8], gv[8], bev[8];
  #pragma unroll
  for (int t=0;t<8;t++){
    int n=t*32+col; bv[t]=bc[n]; gv[t]=gc[n]; bev[t]=bec[n];
  }
  float bcav = (col<8) ? bca[col] : 0.f;

  #pragma unroll
  for (int r=0;r<16;r++){
    int row=(r&3)+8*(r>>2)+4*half;
    float s=0.f, sq=0.f;
    #pragma unroll
    for (int t=0;t<8;t++){
      float v = acc[t][r] + bv[t]; acc[t][r]=v; s += v; sq = fmaf(v,v,sq);
    }
    #pragma unroll
    for (int m=1;m<=16;m<<=1){ s += __shfl_xor(s,m,64); sq += __shfl_xor(sq,m,64); }
    float mu = s*(1.f/256.f);
    float var = fmaf(sq,1.f/256.f, -mu*mu);
    float rin = rsqrtf(var+1e-5f);
    #pragma unroll
    for (int t=0;t<8;t++) acc[t][r] = fmaf((acc[t][r]-mu)*rin, gv[t], bev[t]);
    if (col<8) logit[(y0+row)*12+col] = acc[8][r] + bcav;
  }
  __syncthreads();

  // masked softmax over y (len 128): 32 threads per head
  {
    int h = tid>>5, sub = tid&31;
    float lv[4], ev[4];
    #pragma unroll
    for (int j=0;j<4;j++) lv[j] = logit[(sub+32*j)*12 + h];
    float mx = fmaxf(fmaxf(lv[0],lv[1]), fmaxf(lv[2],lv[3]));
    #pragma unroll
    for (int m=1;m<=16;m<<=1) mx = fmaxf(mx, __shfl_xor(mx,m,64));
    float ssum=0.f;
    #pragma unroll
    for (int j=0;j<4;j++){ ev[j] = __expf(lv[j]-mx)*sm.c.maskv[sub+32*j]; ssum += ev[j]; }
    #pragma unroll
    for (int m=1;m<=16;m<<=1) ssum += __shfl_xor(ssum,m,64);
    float inv = 1.f/(ssum+1e-10f);
    #pragma unroll
    for (int j=0;j<4;j++) logit[(sub+32*j)*12+h] = ev[j]*inv;
  }
  __syncthreads();

  // contraction: sum_y w[y,h] * of[y,n]
  float ctr[8];
  #pragma unroll
  for (int t=0;t<8;t++) ctr[t]=0.f;
  #pragma unroll
  for (int r=0;r<16;r++){
    int row=(r&3)+8*(r>>2)+4*half;
    const float* wr = &logit[(y0+row)*12];
    float4 w0v = *(const float4*)wr;
    float4 w1v = *(const float4*)(wr+4);
    ctr[0]=fmaf(w0v.x,acc[0][r],ctr[0]); ctr[1]=fmaf(w0v.y,acc[1][r],ctr[1]);
    ctr[2]=fmaf(w0v.z,acc[2][r],ctr[2]); ctr[3]=fmaf(w0v.w,acc[3][r],ctr[3]);
    ctr[4]=fmaf(w1v.x,acc[4][r],ctr[4]); ctr[5]=fmaf(w1v.y,acc[5][r],ctr[5]);
    ctr[6]=fmaf(w1v.z,acc[6][r],ctr[6]); ctr[7]=fmaf(w1v.w,acc[7][r],ctr[7]);
  }
  #pragma unroll
  for (int t=0;t<8;t++) ctr[t] += __shfl_xor(ctr[t],32,64);
  if (lane<32){
    #pragma unroll
    for (int t=0;t<8;t++) partial[wave*256 + t*32 + col] = ctr[t];
  }
  __syncthreads();
  float v = partial[tid]+partial[256+tid]+partial[512+tid]+partial[768+tid];
  outc[(size_t)bl*256 + tid] = v;
}

// ---------------------------------------------------------------------------
// Expand body: per (b, 32-y tile): C[x,y,h] = sum_f xf[x,h,f]*yf[y,h,f]
// 16x16x32 MFMA, per-wave LDS transpose (no inner barriers), f32 output.
// ---------------------------------------------------------------------------
DEV void expand_body(FMem& sm, int blk,
    const u16* __restrict__ xf, const u16* __restrict__ yf, float* __restrict__ oute)
{
  int tid=threadIdx.x, lane=tid&63, wave=tid>>6;
  int bi = blk>>4, yt = blk&15;

  #pragma unroll
  for (int i=0;i<4;i++){
    int idx=i*256+tid; int row=idx>>5, c=idx&31;
    uint4 v = *(const uint4*)(yf + ((size_t)(bi*512 + yt*32 + row))*256 + c*8);
    *(uint4*)((char*)sm.e.ytile + row*528 + c*16) = v;
  }
  __syncthreads();

  bf16x8 af[2][8];
  #pragma unroll
  for (int xi=0;xi<2;xi++){
    int x = (wave*2+xi)*16 + (lane&15);
    #pragma unroll
    for (int h=0;h<8;h++)
      af[xi][h] = *(const bf16x8*)(xf + ((size_t)(bi*128+x))*256 + h*32 + (lane>>4)*8);
  }
  float* stw = sm.e.stage[wave];
  #pragma unroll
  for (int xi=0;xi<2;xi++){
    #pragma unroll
    for (int nt=0;nt<2;nt++){
      f32x4v c[8];
      #pragma unroll
      for (int h=0;h<8;h++){
        bf16x8 bv = *(const bf16x8*)((const char*)sm.e.ytile + (nt*16+(lane&15))*528 + (h*32+(lane>>4)*8)*2);
        f32x4v z = {0.f,0.f,0.f,0.f};
        c[h] = __builtin_amdgcn_mfma_f32_16x16x32_bf16(af[xi][h], bv, z, 0,0,0);
      }
      #pragma unroll
      for (int q=0;q<4;q++){
        int xp=(lane>>4)*4+q, yp=lane&15;
        float* sp = &stw[(xp*16+yp)*8];
        float4 v0; v0.x=c[0][q]; v0.y=c[1][q]; v0.z=c[2][q]; v0.w=c[3][q];
        float4 v1; v1.x=c[4][q]; v1.y=c[5][q]; v1.z=c[6][q]; v1.w=c[7][q];
        *(float4*)sp = v0;
        *(float4*)(sp+4) = v1;
      }
      // per-wave stage: no barrier needed (wave-order + lgkmcnt)
      #pragma unroll
      for (int j=0;j<4;j++){
        int pi=j*64+lane, xp=pi>>4, yp=pi&15;
        const float* sp = &stw[(xp*16+yp)*8];
        float4 a = *(const float4*)sp;
        float4 b2 = *(const float4*)(sp+4);
        size_t x=(size_t)(wave*2+xi)*16+xp, y=(size_t)yt*32+nt*16+yp;
        float* po = oute + (((size_t)bi*128+x)*512 + y)*8;
        *(float4*)po = a;
        *(float4*)(po+4) = b2;
      }
    }
  }
}

// ---------------------------------------------------------------------------
// Edges body: gather 64 edges' concat rows -> bf16 LDS (XOR swizzle),
// 4 waves: wave w = rows (w&1)*32, out tile (w>>1). 32x32x16 MFMA K=512,
// bias+lrelu, f32 atomicAdd scatter.
// ---------------------------------------------------------------------------
DEV void edges_body(FMem& sm, int blk,
    const float* __restrict__ lig, const int* __restrict__ eb, const int* __restrict__ es,
    const int* __restrict__ ed, const u16* __restrict__ Wp, const float* __restrict__ bias,
    float* __restrict__ outl)
{
  char* slab = sm.eslab;
  int tid=threadIdx.x, lane=tid&63, wave=tid>>6;   // 4 waves, 16 edges each
  int e0 = blk*64;
  int ge = e0 + wave*16 + (lane&15);
  int b0=eb[ge], s0=es[ge], d0=ed[ge];
  long long ps = (long long)(uintptr_t)(lig + ((size_t)(b0*128+s0))*256);
  long long pd = (long long)(uintptr_t)(lig + ((size_t)(b0*128+d0))*256);
  #pragma unroll 4
  for (int i=0;i<16;i++){
    int ri = wave*16 + i;
    const float* sp = (const float*)(uintptr_t)__shfl(ps, i, 16);
    const float* dp = (const float*)(uintptr_t)__shfl(pd, i, 16);
    #pragma unroll
    for (int j=0;j<2;j++){
      const float* base = j ? dp : sp;
      float4 v = *(const float4*)(base + lane*4);
      uint2 pk = cvt4(v);
      int g = j*32 + (lane>>1);
      *(uint2*)(slab + (size_t)ri*1024 + ((g ^ (ri&63))<<4) + (lane&1)*8) = pk;
    }
  }
  __syncthreads();

  f32x16 acc;
  #pragma unroll
  for (int i=0;i<16;i++) acc[i]=0.f;
  int arow = (wave&1)*32 + (lane&31);
  int axor = arow & 63;
  int half = lane>>5;
  int t = wave>>1;
  const u16* wl = Wp + lane*8 + (size_t)t*16384;

  uint4 raw = *(const uint4*)(slab + (size_t)arow*1024 + ((half ^ axor)<<4));
  bf16x8 w = *(const bf16x8*)(wl);
  for (int kk=0;kk<32;kk++){
    int kn = (kk+1)&31;
    uint4 rn = *(const uint4*)(slab + (size_t)arow*1024 + (((kn*2+half) ^ axor)<<4));
    bf16x8 nw = *(const bf16x8*)(wl + (size_t)kn*512);
    __builtin_amdgcn_sched_barrier(0);
    bf16x8 a = __builtin_bit_cast(bf16x8, raw);    // lrelu is AFTER linear here
    acc = __builtin_amdgcn_mfma_f32_32x32x16_bf16(a, w, acc, 0,0,0);
    raw=rn; w=nw;
  }
  int col = lane&31;
  float bv = bias[t*32+col];
  #pragma unroll
  for (int r=0;r<16;r++){
    int row=(r&3)+8*(r>>2)+4*half;
    int ee = e0 + (wave&1)*32 + row;
    int bb=eb[ee], ss=es[ee], dd=ed[ee];
    float* cell = outl + (((size_t)(bb*128+ss))*128 + (size_t)dd)*64;
    float v = acc[r] + bv;
    v = fmaxf(v, 0.01f*v);
    atomicAdd(cell + t*32 + col, v);
  }
}

// ---------------------------------------------------------------------------
// Fused launch: blocks [0,256)=edges, [256,512)=expand, [512,2560)=contract.
// Short latency-bound blocks issue first and overlap under the contract stream.
// ---------------------------------------------------------------------------
__global__ __launch_bounds__(256,2) void k_fused(
    const float* __restrict__ ll, const void* __restrict__ maskp,
    const u16* __restrict__ wpc, const float* __restrict__ bc, const float* __restrict__ bca,
    const float* __restrict__ gc, const float* __restrict__ bec,
    const int* __restrict__ flags, float* __restrict__ outc,
    const u16* __restrict__ xf, const u16* __restrict__ yf, float* __restrict__ oute,
    const float* __restrict__ lig, const int* __restrict__ eb, const int* __restrict__ es,
    const int* __restrict__ ed, const u16* __restrict__ wpe, const float* __restrict__ be,
    float* __restrict__ outl)
{
  __shared__ __attribute__((aligned(16))) FMem sm;
  int bid = blockIdx.x;
  if (bid < 256)       edges_body(sm, bid, lig, eb, es, ed, wpe, be, outl);
  else if (bid < 512)  expand_body(sm, bid-256, xf, yf, oute);
  else                 contract_body(sm, bid-512, ll, maskp, wpc, bc, bca, gc, bec, flags, outc);
}

// ---------------------------------------------------------------------------
// NormAndLinear for lig_feat (blocks 0..15 -> xf) and rec_feat (16..79 -> yf).
// Depth-1 pipelined kk loop.
// ---------------------------------------------------------------------------
__global__ __launch_bounds__(256,2) void k_nl(
    const float* __restrict__ lig, const float* __restrict__ rec,
    const u16* __restrict__ Wpx, const u16* __restrict__ Wpy,
    const float* __restrict__ bx, const float* __restrict__ gx, const float* __restrict__ ex,
    const float* __restrict__ by, const float* __restrict__ gy, const float* __restrict__ ey,
    u16* __restrict__ xf, u16* __restrict__ yf)
{
  __shared__ __attribute__((aligned(16))) char slab[65536];
  int tid=threadIdx.x, lane=tid&63, wave=tid>>6;
  bool isx = blockIdx.x < 16;
  int bb = isx ? blockIdx.x : blockIdx.x - 16;
  const float* src  = isx ? lig : rec;
  const u16*  Wp    = isx ? Wpx : Wpy;
  const float* bias = isx ? bx : by;
  const float* g    = isx ? gx : gy;
  const float* beta = isx ? ex : ey;
  u16* dst          = isx ? xf : yf;

  const float* s0 = src + (size_t)bb*(128*256);
  #pragma unroll 8
  for (int it=0;it<32;it++){
    int row = wave*32 + it;
    float4 v = *(const float4*)(s0 + row*256 + lane*4);
    uint2 pk = cvt4(v);
    *(uint2*)(slab + row*512 + ((((lane>>1) ^ (row&31)))<<4) + (lane&1)*8) = pk;
  }
  __syncthreads();

  f32x16 acc[8];
  #pragma unroll
  for (int t=0;t<8;t++)
    #pragma unroll
    for (int i=0;i<16;i++) acc[t][i]=0.f;
  int y0 = wave*32;
  int arow = y0 + (lane&31);
  int axor = arow & 31;
  int half = lane>>5;
  const u16* wl = Wp + lane*8;

  uint4 raw = *(const uint4*)(slab + arow*512 + ((half ^ axor)<<4));
  bf16x8 w0 = *(const bf16x8*)(wl);
  bf16x8 w1 = *(const bf16x8*)(wl + 8192);
  bf16x8 w2 = *(const bf16x8*)(wl + 16384);
  bf16x8 w3 = *(const bf16x8*)(wl + 24576);
  bf16x8 w4 = *(const bf16x8*)(wl + 32768);
  bf16x8 w5 = *(const bf16x8*)(wl + 40960);
  bf16x8 w6 = *(const bf16x8*)(wl + 49152);
  bf16x8 w7 = *(const bf16x8*)(wl + 57344);

  #pragma unroll 4
  for (int kk=0;kk<16;kk++){
    int kn = (kk+1)&15;
    uint4 rawn = *(const uint4*)(slab + arow*512 + (((kn*2+half) ^ axor)<<4));
    const u16* wkn = wl + (size_t)kn*512;
    bf16x8 n0 = *(const bf16x8*)(wkn);
    bf16x8 n1 = *(const bf16x8*)(wkn + 8192);
    bf16x8 n2 = *(const bf16x8*)(wkn + 16384);
    bf16x8 n3 = *(const bf16x8*)(wkn + 24576);
    bf16x8 n4 = *(const bf16x8*)(wkn + 32768);
    bf16x8 n5 = *(const bf16x8*)(wkn + 40960);
    bf16x8 n6 = *(const bf16x8*)(wkn + 49152);
    bf16x8 n7 = *(const bf16x8*)(wkn + 57344);
    __builtin_amdgcn_sched_barrier(0);
    uint4 t4; t4.x=lrelu_pk(raw.x); t4.y=lrelu_pk(raw.y); t4.z=lrelu_pk(raw.z); t4.w=lrelu_pk(raw.w);
    bf16x8 a = __builtin_bit_cast(bf16x8, t4);
    acc[0] = __builtin_amdgcn_mfma_f32_32x32x16_bf16(a, w0, acc[0], 0,0,0);
    acc[1] = __builtin_amdgcn_mfma_f32_32x32x16_bf16(a, w1, acc[1], 0,0,0);
    acc[2] = __builtin_amdgcn_mfma_f32_32x32x16_bf16(a, w2, acc[2], 0,0,0);
    acc[3] = __builtin_amdgcn_mfma_f32_32x32x16_bf16(a, w3, acc[3], 0,0,0);
    acc[4] = __builtin_amdgcn_mfma_f32_32x32x16_bf16(a, w4, acc[4], 0,0,0);
    acc[5] = __builtin_amdgcn_mfma_f32_32x32x16_bf16(a, w5, acc[5], 0,0,0);
    acc[6] = __builtin_amdgcn_mfma_f32_32x32x16_bf16(a, w6, acc[6], 0,0,0);
    acc[7] = __builtin_amdgcn_mfma_f32_32x32x16_bf16(a, w7, acc[7], 0,0,0);
    raw=rawn;
    w0=n0; w1=n1; w2=n2; w3=n3; w4=n4; w5=n5; w6=n6; w7=n7;
  }
  int col = lane & 31;
  float bv[8], gv[8], bev[8];
  #pragma unroll
  for (int t=0;t<8;t++){
    int n=t*32+col; bv[t]=bias[n]; gv[t]=g[n]; bev[t]=beta[n];
  }
  #pragma unroll
  for (int r=0;r<16;r++){
    int row=(r&3)+8*(r>>2)+4*half;
    float s=0.f, sq=0.f;
    #pragma unroll
    for (int t=0;t<8;t++){
      float v = acc[t][r] + bv[t]; acc[t][r]=v; s += v; sq = fmaf(v,v,sq);
    }
    #pragma unroll
    for (int m=1;m<=16;m<<=1){ s += __shfl_xor(s,m,64); sq += __shfl_xor(sq,m,64); }
    float mu = s*(1.f/256.f);
    float var = fmaf(sq,1.f/256.f, -mu*mu);
    float rin = rsqrtf(var+1e-5f);
    size_t rowg = (size_t)bb*128 + y0 + row;
    #pragma unroll
    for (int t=0;t<8;t++){
      float v = fmaf((acc[t][r]-mu)*rin, gv[t], bev[t]);
      dst[rowg*256 + t*32 + col] = f2bf(v);
    }
  }
}

// ---------------------------------------------------------------------------
extern "C" void kernel_launch(void* const* d_in, const int* in_sizes, int n_in,
                              void* d_out, int out_size, void* d_ws, size_t ws_size,
                              hipStream_t stream)
{
  (void)in_sizes; (void)n_in; (void)out_size; (void)ws_size;
  const float* ll  = (const float*)d_in[0];
  const float* lig = (const float*)d_in[1];
  const float* rec = (const float*)d_in[2];
  const void* mask = d_in[3];
  const int* eb = (const int*)d_in[4];
  const int* es = (const int*)d_in[5];
  const int* ed = (const int*)d_in[6];
  const float* Wc  =(const float*)d_in[7];  const float* bc  =(const float*)d_in[8];
  const float* gc  =(const float*)d_in[9];  const float* bec =(const float*)d_in[10];
  const float* Wca =(const float*)d_in[11]; const float* bca =(const float*)d_in[12];
  const float* Wex =(const float*)d_in[13]; const float* bex =(const float*)d_in[14];
  const float* gex =(const float*)d_in[15]; const float* beex=(const float*)d_in[16];
  const float* Wey =(const float*)d_in[17]; const float* bey =(const float*)d_in[18];
  const float* gey =(const float*)d_in[19]; const float* beey=(const float*)d_in[20];
  const float* We  =(const float*)d_in[21]; const float* be  =(const float*)d_in[22];

  float* outc = (float*)d_out;
  float* oute = outc + 524288;          // (B,L,R,H)
  float* outl = outc + 8912896;         // (B,L,L,FE)

  char* ws = (char*)d_ws;
  int* flags = (int*)ws;
  u16* wpc = (u16*)(ws + 4096);         // 147456 B
  u16* wpx = (u16*)(ws + 151552);       // 131072 B
  u16* wpy = (u16*)(ws + 282624);       // 131072 B
  u16* wpe = (u16*)(ws + 413696);       //  65536 B
  u16* xf  = (u16*)(ws + 479232);       // 1 MB bf16
  u16* yf  = (u16*)(ws + 1527808);      // 4 MB bf16 (ends ~5.5 MB)

  hipLaunchKernelGGL(k_prepack, dim3(288), dim3(256), 0, stream,
                     Wc, Wca, Wex, Wey, We, (const unsigned char*)mask,
                     wpc, wpx, wpy, wpe, flags, outl);
  hipLaunchKernelGGL(k_nl, dim3(80), dim3(256), 0, stream,
                     lig, rec, wpx, wpy, bex, gex, beex, bey, gey, beey, xf, yf);
  hipLaunchKernelGGL(k_fused, dim3(2560), dim3(256), 0, stream,
                     ll, mask, wpc, bc, bca, gc, bec, flags, outc,
                     xf, yf, oute, lig, eb, es, ed, wpe, be, outl);
}